// Round 1
// baseline (50.979 us; speedup 1.0000x reference)
//
#include <hip/hip_runtime.h>
#include <math.h>

#define N_PIX   65536
#define NWL     112
#define NW      111          // end = N_WL - 1 : columns 0..110 used
#define NATM    84
#define MAIN_BLOCKS 1024
#define THREADS 256          // 4 waves per block

// K = WFA_CONSTANT * LAMBDA0^2 * G_FACTOR (computed in double, used as f32 like reference)
__device__ __constant__ double K_CONST = 4.6686e-13 * 6301.5 * 6301.5 * 1.5;

__global__ __launch_bounds__(THREADS) void wfa_main_kernel(
    const float* __restrict__ stokes,   // (N_PIX, 4, 112)
    const float* __restrict__ pred,     // (N_PIX, 84)
    const float* __restrict__ targ,     // (N_PIX, 84)
    const float* __restrict__ wl,       // (112)
    double* __restrict__ partials)      // (gridDim.x, 3): baseSum, cnt, wdiffSum
{
    __shared__ float  sDwl[NW];
    __shared__ float  sI[4][NWL];
    __shared__ double sB[THREADS], sC[THREADS], sW[THREADS];

    const int tid  = threadIdx.x;
    const int lane = tid & 63;
    const int wv   = tid >> 6;

    // Per-block precompute of gradient(wl) over wl[0:111] (faithful to jnp.gradient)
    if (tid < NW) {
        float d;
        if (tid == 0)            d = wl[1] - wl[0];
        else if (tid == NW - 1)  d = wl[NW - 1] - wl[NW - 2];
        else                     d = 0.5f * (wl[tid + 1] - wl[tid - 1]);
        sDwl[tid] = d;
    }
    __syncthreads();

    const int waveGlobal = blockIdx.x * 4 + wv;
    const int nWaves     = gridDim.x * 4;
    const int iters      = (N_PIX + nWaves - 1) / nWaves;

    double accBase = 0.0;   // per-thread |pred-targ| partial
    double accCnt  = 0.0;   // lane 0 only
    double accWd   = 0.0;   // lane 0 only

    for (int it = 0; it < iters; ++it) {
        const int p = waveGlobal + it * nWaves;
        const bool active = (p < N_PIX);

        float v0 = 0.f, v1 = 0.f;
        if (active) {
            const float* srow = stokes + (size_t)p * (4 * NWL);
            // Stage I row (112 floats) in this wave's LDS slice
            sI[wv][lane] = srow[lane];
            if (lane < NWL - 64) sI[wv][lane + 64] = srow[lane + 64];
            // V loads (only columns 0..110 contribute)
            v0 = srow[3 * NWL + lane];                       // j = lane (always < 111)
            if (lane < NW - 64) v1 = srow[3 * NWL + lane + 64]; // j = lane+64 <= 110
        }
        __syncthreads();  // uniform across block (all waves same trip count)

        float sdI = 0.f, sV = 0.f, sdd = 0.f, sdv = 0.f;
        if (active) {
            // j = lane  (0..63): edge only at j==0
            {
                const int j = lane;
                float g;
                if (j == 0) g = sI[wv][1] - sI[wv][0];
                else        g = 0.5f * (sI[wv][j + 1] - sI[wv][j - 1]);
                const float dI = g / sDwl[j];
                sdI += dI; sdd += dI * dI; sV += v0; sdv += dI * v0;
            }
            // j = lane + 64 (64..110 for lane<47): edge at j==110
            if (lane < NW - 64) {
                const int j = lane + 64;
                float g;
                if (j == NW - 1) g = sI[wv][NW - 1] - sI[wv][NW - 2];
                else             g = 0.5f * (sI[wv][j + 1] - sI[wv][j - 1]);
                const float dI = g / sDwl[j];
                sdI += dI; sdd += dI * dI; sV += v1; sdv += dI * v1;
            }
        }

        // Wave butterfly reduction of the 4 regression sums (f32, deterministic)
        #pragma unroll
        for (int off = 32; off; off >>= 1) {
            sdI += __shfl_xor(sdI, off);
            sV  += __shfl_xor(sV,  off);
            sdd += __shfl_xor(sdd, off);
            sdv += __shfl_xor(sdv, off);
        }

        if (active) {
            // base-loss partial + predicted_blos for this pixel
            const float* pp = pred + (size_t)p * NATM;
            const float* tt = targ + (size_t)p * NATM;
            const float pv0 = pp[lane];                    // lane < 64 < 84
            float bsum = fabsf(pv0 - tt[lane]);
            if (lane < NATM - 64)                           // lanes 0..19
                bsum += fabsf(pp[lane + 64] - tt[lane + 64]);
            accBase += (double)bsum;

            // predicted_blos = mean of flat elems 3,7,11 (itau 0..2, mag 3)
            const float a0 = __shfl(pv0, 3);
            const float a1 = __shfl(pv0, 7);
            const float a2 = __shfl(pv0, 11);
            const float pblos = (a0 + a1 + a2) / 3.0f;

            // WFA regression -> blos
            const float n     = (float)NW;
            const float denom = n * sdd - sdI * sdI;
            const float coef  = (n * sdv - sdI * sV) / denom;
            const float wfa   = -coef / (float)K_CONST;

            const float mask = (fabsf(wfa) < 1.0e6f) ? 1.0f : 0.0f;
            const float logp = log10f(fabsf(pblos) + 1e-10f);
            const float logw = log10f(fabsf(wfa)   + 1e-10f);
            const float d    = fabsf(logp - logw);

            if (lane == 0) { accCnt += (double)mask; accWd += (double)(mask * d); }
        }
        __syncthreads();  // protect sI before next iteration's overwrite
    }

    // Block reduction (double), one 3-double partial per block
    sB[tid] = accBase; sC[tid] = accCnt; sW[tid] = accWd;
    __syncthreads();
    #pragma unroll
    for (int s = 128; s; s >>= 1) {
        if (tid < s) {
            sB[tid] += sB[tid + s];
            sC[tid] += sC[tid + s];
            sW[tid] += sW[tid + s];
        }
        __syncthreads();
    }
    if (tid == 0) {
        partials[(size_t)blockIdx.x * 3 + 0] = sB[0];
        partials[(size_t)blockIdx.x * 3 + 1] = sC[0];
        partials[(size_t)blockIdx.x * 3 + 2] = sW[0];
    }
}

__global__ __launch_bounds__(THREADS) void wfa_final_kernel(
    const double* __restrict__ partials, int nPart, float* __restrict__ out)
{
    __shared__ double sB[THREADS], sC[THREADS], sW[THREADS];
    const int tid = threadIdx.x;
    double b = 0.0, c = 0.0, w = 0.0;
    for (int i = tid; i < nPart; i += THREADS) {
        b += partials[(size_t)i * 3 + 0];
        c += partials[(size_t)i * 3 + 1];
        w += partials[(size_t)i * 3 + 2];
    }
    sB[tid] = b; sC[tid] = c; sW[tid] = w;
    __syncthreads();
    #pragma unroll
    for (int s = 128; s; s >>= 1) {
        if (tid < s) {
            sB[tid] += sB[tid + s];
            sC[tid] += sC[tid + s];
            sW[tid] += sW[tid + s];
        }
        __syncthreads();
    }
    if (tid == 0) {
        const double base     = sB[0] / ((double)N_PIX * (double)NATM);
        const double cnt      = sC[0];
        const double wfa_mean = sW[0] / fmax(cnt, 1.0);
        const bool   apply    = (base < 10.0) && (cnt > 0.0);
        const double wfa_loss = apply ? wfa_mean : 0.0;
        const double total    = apply ? (0.5 * base + 0.5 * wfa_mean) : base;
        out[0] = (float)total;
        out[1] = (float)base;
        out[2] = (float)wfa_loss;
    }
}

extern "C" void kernel_launch(void* const* d_in, const int* in_sizes, int n_in,
                              void* d_out, int out_size, void* d_ws, size_t ws_size,
                              hipStream_t stream) {
    (void)in_sizes; (void)n_in; (void)out_size;

    const float* stokes = (const float*)d_in[0];   // (65536, 4, 112) f32
    const float* pred   = (const float*)d_in[1];   // (65536, 84)     f32
    const float* targ   = (const float*)d_in[2];   // (65536, 84)     f32
    const float* wl     = (const float*)d_in[3];   // (112)           f32
    float* out          = (float*)d_out;           // 3 f32 scalars
    double* partials    = (double*)d_ws;

    int nBlocks = MAIN_BLOCKS;
    const size_t need = (size_t)nBlocks * 3 * sizeof(double);
    if (ws_size < need) {
        nBlocks = (int)(ws_size / (3 * sizeof(double)));
        if (nBlocks < 1) nBlocks = 1;
    }

    wfa_main_kernel<<<nBlocks, THREADS, 0, stream>>>(stokes, pred, targ, wl, partials);
    wfa_final_kernel<<<1, THREADS, 0, stream>>>(partials, nBlocks, out);
}

// Round 2
// 31.105 us; speedup vs baseline: 1.6390x; 1.6390x over previous
//
#include <hip/hip_runtime.h>
#include <math.h>

#define N_PIX   65536
#define NWL     112
#define NW      111          // columns 0..110 used
#define NATM    84
#define BLOCKS  2048
#define THREADS 256          // 4 waves/block
#define ITERS   4            // pixels per wave = 2 * ITERS = 8

// K = WFA_CONSTANT * LAMBDA0^2 * G_FACTOR, rounded to f32 exactly like the reference
#define KF ((float)(4.6686e-13 * 6301.5 * 6301.5 * 1.5))

__global__ __launch_bounds__(THREADS) void wfa_main(
    const float* __restrict__ stokes,   // (N_PIX, 4, 112)
    const float* __restrict__ pred,     // (N_PIX, 84)
    const float* __restrict__ targ,     // (N_PIX, 84)
    const float* __restrict__ wl,       // (112)
    double* __restrict__ partials)      // (BLOCKS, 3)
{
    const int tid  = threadIdx.x;
    const int lane = tid & 63;
    const int q    = lane & 31;   // position within half-wave
    const int h    = lane & 32;   // 0 = pixel A half, 32 = pixel B half
    const bool ioL = q < 28;      // lanes carrying I/V float4s (28*4 = 112)
    const bool pL  = q < 21;      // lanes carrying pred/targ float4s (21*4 = 84)

    // ---- loop-invariant: reciprocal of gradient(wl) per element (4/lane) ----
    float rd0 = 0.f, rd1 = 0.f, rd2 = 0.f, rd3 = 0.f;
    {
        float4 w = make_float4(0.f, 0.f, 0.f, 0.f);
        if (ioL) w = *reinterpret_cast<const float4*>(wl + 4 * q);
        const float wprev = __shfl_up(w.w, 1);    // wl[4q-1]
        const float wnext = __shfl_down(w.x, 1);  // wl[4q+4]
        const float dwl0 = (q == 0)  ? (w.y - w.x) : 0.5f * (w.y - wprev);
        const float dwl1 = 0.5f * (w.z - w.x);
        const float dwl2 = (q == 27) ? (w.z - w.y) : 0.5f * (w.w - w.y); // j=110 edge
        const float dwl3 = (q == 27) ? 1.0f        : 0.5f * (wnext - w.z); // j=111 unused
        if (ioL) { rd0 = 1.0f / dwl0; rd1 = 1.0f / dwl1; rd2 = 1.0f / dwl2; rd3 = 1.0f / dwl3; }
    }

    const int waveGlobal = blockIdx.x * (THREADS / 64) + (tid >> 6);

    double accBase = 0.0;  // all lanes
    double accCnt  = 0.0;  // q==0 lanes only
    double accWd   = 0.0;  // q==0 lanes only

    #pragma unroll
    for (int it = 0; it < ITERS; ++it) {
        const int pix = waveGlobal * (2 * ITERS) + it * 2 + (h ? 1 : 0);
        const float* srow = stokes + (size_t)pix * (4 * NWL);

        float4 I4 = make_float4(0.f, 0.f, 0.f, 0.f);
        float4 V4 = make_float4(0.f, 0.f, 0.f, 0.f);
        float4 P4 = make_float4(0.f, 0.f, 0.f, 0.f);
        float4 T4 = make_float4(0.f, 0.f, 0.f, 0.f);
        if (ioL) {
            I4 = *reinterpret_cast<const float4*>(srow + 4 * q);
            V4 = *reinterpret_cast<const float4*>(srow + 3 * NWL + 4 * q);
        }
        if (pL) {
            P4 = *reinterpret_cast<const float4*>(pred + (size_t)pix * NATM + 4 * q);
            T4 = *reinterpret_cast<const float4*>(targ + (size_t)pix * NATM + 4 * q);
        }

        // jnp.gradient(I) via neighbor shuffles (lane q holds j = 4q..4q+3)
        const float iprev = __shfl_up(I4.w, 1);    // I[4q-1]
        const float inext = __shfl_down(I4.x, 1);  // I[4q+4]
        const float g0 = (q == 0)  ? (I4.y - I4.x) : 0.5f * (I4.y - iprev);
        const float g1 = 0.5f * (I4.z - I4.x);
        const float g2 = (q == 27) ? (I4.z - I4.y) : 0.5f * (I4.w - I4.y);
        const float g3 = 0.5f * (inext - I4.z);
        float d0 = g0 * rd0, d1 = g1 * rd1, d2 = g2 * rd2, d3 = g3 * rd3;
        if (q == 27) { d3 = 0.f; V4.w = 0.f; }  // j=111 excluded from all sums
        if (!ioL)    { d0 = d1 = d2 = d3 = 0.f; }

        float sdI = d0 + d1 + d2 + d3;
        float sV  = V4.x + V4.y + V4.z + V4.w;
        float sdd = d0 * d0 + d1 * d1 + d2 * d2 + d3 * d3;
        float sdv = d0 * V4.x + d1 * V4.y + d2 * V4.z + d3 * V4.w;

        // butterfly within each 32-lane half (offsets < 32 never cross halves)
        #pragma unroll
        for (int off = 16; off; off >>= 1) {
            sdI += __shfl_xor(sdI, off);
            sV  += __shfl_xor(sV,  off);
            sdd += __shfl_xor(sdd, off);
            sdv += __shfl_xor(sdv, off);
        }

        // base-loss partial (inactive lanes contribute exact zeros)
        const float bsum = fabsf(P4.x - T4.x) + fabsf(P4.y - T4.y) +
                           fabsf(P4.z - T4.z) + fabsf(P4.w - T4.w);
        accBase += (double)bsum;

        // predicted_blos: flat elems 3,7,11 = .w of lanes h+0, h+1, h+2
        const float pw = P4.w;
        const float a0 = __shfl(pw, h + 0);
        const float a1 = __shfl(pw, h + 1);
        const float a2 = __shfl(pw, h + 2);

        if (q == 0) {
            const float pblos = (a0 + a1 + a2) / 3.0f;
            const float nf    = (float)NW;
            const float coef  = (nf * sdv - sdI * sV) / (nf * sdd - sdI * sdI);
            const float wfa   = -coef / KF;
            const float mask  = (fabsf(wfa) < 1.0e6f) ? 1.0f : 0.0f;
            const float lp    = log10f(fabsf(pblos) + 1e-10f);
            const float lw    = log10f(fabsf(wfa)   + 1e-10f);
            accCnt += (double)mask;
            accWd  += (double)(mask * fabsf(lp - lw));
        }
    }

    // ---- block reduction (barriers only here) ----
    __shared__ double sB[THREADS], sC[THREADS], sW[THREADS];
    sB[tid] = accBase; sC[tid] = accCnt; sW[tid] = accWd;
    __syncthreads();
    #pragma unroll
    for (int s = 128; s; s >>= 1) {
        if (tid < s) {
            sB[tid] += sB[tid + s];
            sC[tid] += sC[tid + s];
            sW[tid] += sW[tid + s];
        }
        __syncthreads();
    }
    if (tid == 0) {
        partials[(size_t)blockIdx.x * 3 + 0] = sB[0];
        partials[(size_t)blockIdx.x * 3 + 1] = sC[0];
        partials[(size_t)blockIdx.x * 3 + 2] = sW[0];
    }
}

__global__ __launch_bounds__(THREADS) void wfa_final(
    const double* __restrict__ partials, int nPart, float* __restrict__ out)
{
    __shared__ double sB[THREADS], sC[THREADS], sW[THREADS];
    const int tid = threadIdx.x;
    double b = 0.0, c = 0.0, w = 0.0;
    for (int i = tid; i < nPart; i += THREADS) {
        b += partials[(size_t)i * 3 + 0];
        c += partials[(size_t)i * 3 + 1];
        w += partials[(size_t)i * 3 + 2];
    }
    sB[tid] = b; sC[tid] = c; sW[tid] = w;
    __syncthreads();
    #pragma unroll
    for (int s = 128; s; s >>= 1) {
        if (tid < s) {
            sB[tid] += sB[tid + s];
            sC[tid] += sC[tid + s];
            sW[tid] += sW[tid + s];
        }
        __syncthreads();
    }
    if (tid == 0) {
        const double base     = sB[0] / ((double)N_PIX * (double)NATM);
        const double cnt      = sC[0];
        const double wfa_mean = sW[0] / fmax(cnt, 1.0);
        const bool   apply    = (base < 10.0) && (cnt > 0.0);
        const double wfa_loss = apply ? wfa_mean : 0.0;
        const double total    = apply ? (0.5 * base + 0.5 * wfa_mean) : base;
        out[0] = (float)total;
        out[1] = (float)base;
        out[2] = (float)wfa_loss;
    }
}

extern "C" void kernel_launch(void* const* d_in, const int* in_sizes, int n_in,
                              void* d_out, int out_size, void* d_ws, size_t ws_size,
                              hipStream_t stream) {
    (void)in_sizes; (void)n_in; (void)out_size;

    const float* stokes = (const float*)d_in[0];
    const float* pred   = (const float*)d_in[1];
    const float* targ   = (const float*)d_in[2];
    const float* wl     = (const float*)d_in[3];
    float* out          = (float*)d_out;
    double* partials    = (double*)d_ws;

    int nBlocks = BLOCKS;
    const size_t need = (size_t)nBlocks * 3 * sizeof(double);
    if (ws_size < need) {
        nBlocks = (int)(ws_size / (3 * sizeof(double)));
        if (nBlocks < 1) nBlocks = 1;
    }

    wfa_main<<<nBlocks, THREADS, 0, stream>>>(stokes, pred, targ, wl, partials);
    wfa_final<<<1, THREADS, 0, stream>>>(partials, nBlocks, out);
}